// Round 2
// baseline (2447.855 us; speedup 1.0000x reference)
//
#include <hip/hip_runtime.h>
#include <cstdint>
#include <cstddef>

#define T_STEPS 1024
#define NB 64
#define DIN 256
#define DH 256
#define DW 512            // DIN + DH (row width of each W)
#define G4 1024           // 4*DH gate rows
#define KR 192            // K-range of recurrent weights held in registers
#define KRH (KR/2)        // 96 h2 registers
#define NTAIL ((DH-KR)/8) // 8 LDS chunks of 8 f16 per row

typedef _Float16 h2 __attribute__((ext_vector_type(2)));
typedef _Float16 h4 __attribute__((ext_vector_type(4)));
typedef _Float16 h8 __attribute__((ext_vector_type(8)));
typedef float f4 __attribute__((ext_vector_type(4)));

// Build h2 = (v[2m], v[2m+1]) from an h8. Dynamic subscripts constant-fold
// after #pragma unroll (shufflevector requires parse-time constants).
static __device__ __forceinline__ h2 sl2(h8 v, int m) {
  h2 r; r[0] = v[2 * m]; r[1] = v[2 * m + 1]; return r;
}
static __device__ __forceinline__ h2 sl2_4(h4 v, int m) {
  h2 r; r[0] = v[2 * m]; r[1] = v[2 * m + 1]; return r;
}

static __device__ __forceinline__ float fdot2(h2 a, h2 b, float c) {
#if __has_builtin(__builtin_amdgcn_fdot2)
  return __builtin_amdgcn_fdot2(a, b, c, false);
#else
  return c + (float)a[0]*(float)b[0] + (float)a[1]*(float)b[1];
#endif
}

static __device__ __forceinline__ float rcp_(float x) {
#if __has_builtin(__builtin_amdgcn_rcpf)
  return __builtin_amdgcn_rcpf(x);
#else
  return 1.0f / x;
#endif
}

static __device__ __forceinline__ float sigmoid_(float x) {
  x = fminf(fmaxf(x, -30.f), 30.f);
  return rcp_(1.f + __expf(-x));
}
static __device__ __forceinline__ float tanh_(float x) {
  x = fminf(fmaxf(x, -15.f), 15.f);
  float e = __expf(2.f * x);
  return 1.f - 2.f * rcp_(e + 1.f);
}

// ---------------------------------------------------------------------------
// Convert x-part of W (cols [0,256)) to f16, k-pair-major transposed:
// wxhT[kp][gr] = (W[gr][2kp], W[gr][2kp+1]),  kp in [0,128), gr = gate*256+j
// ---------------------------------------------------------------------------
__global__ void kconv_w(const float* __restrict__ Wf, const float* __restrict__ Wi,
                        const float* __restrict__ Wg, const float* __restrict__ Wo,
                        h2* __restrict__ wxhT) {
  int kp = blockIdx.x >> 2;
  int gate = blockIdx.x & 3;
  int j = threadIdx.x;
  const float* W = gate == 0 ? Wf : gate == 1 ? Wi : gate == 2 ? Wg : Wo;
  const float* row = W + (size_t)j * DW;
  h2 v; v[0] = (_Float16)row[2*kp]; v[1] = (_Float16)row[2*kp + 1];
  wxhT[(size_t)kp * G4 + gate * DH + j] = v;
}

// ---------------------------------------------------------------------------
// Phase 1: Xg[t_local][b][gr] = x[t][b][:] . Wx[gr][:] + bias[gr]   (f16 out)
// grid: tc*4 blocks; block = (tb = bid>>2 [time within chunk], gb = bid&3 [gate])
// 256 threads: tg = tid&31 (8 gates each), tr = tid>>5 (8 batch rows each)
// ---------------------------------------------------------------------------
__launch_bounds__(256, 2)
__global__ void kxgemm(const float* __restrict__ x,
                       const h2* __restrict__ wxhT,
                       const float* __restrict__ bf, const float* __restrict__ bi,
                       const float* __restrict__ bg, const float* __restrict__ bo,
                       _Float16* __restrict__ Xg,
                       int t0) {
  __shared__ h2 xs[64 * 64];    // [row 64][kp 64]  16KB (per K-stage)
  __shared__ h2 wsT[64 * 256];  // [kp 64][gate 256] 64KB (per K-stage)

  int tid = threadIdx.x;
  int tg = tid & 31, tr = tid >> 5;
  int tb = blockIdx.x >> 2, gb = blockIdx.x & 3;
  size_t xrow0 = ((size_t)(t0 + tb)) * NB;

  float acc[8][8];
#pragma unroll
  for (int r = 0; r < 8; ++r)
#pragma unroll
    for (int g = 0; g < 8; ++g) acc[r][g] = 0.f;

  for (int ks = 0; ks < 2; ++ks) {
    // stage x tile: 64 rows x 128 k (fp32 -> f16)
#pragma unroll
    for (int i = 0; i < 8; ++i) {
      int idx = tid + 256 * i;
      int r = idx >> 5, k4 = idx & 31;
      f4 v = *(const f4*)(x + (xrow0 + r) * DIN + ks * 128 + k4 * 4);
      h4 p;
      p[0] = (_Float16)v[0]; p[1] = (_Float16)v[1];
      p[2] = (_Float16)v[2]; p[3] = (_Float16)v[3];
      *(h4*)(void*)(xs + (size_t)r * 64 + 2 * k4) = p;
    }
    // stage W tile: 64 kp x 256 gates (already f16, k-pair-major)
#pragma unroll
    for (int i = 0; i < 16; ++i) {
      int idx = tid + 256 * i;
      int kp = idx >> 6, g4 = idx & 63;
      f4 v = *(const f4*)(const void*)(wxhT + (size_t)(ks * 64 + kp) * G4 + gb * DH + g4 * 4);
      *(f4*)(void*)(wsT + (size_t)kp * 256 + g4 * 4) = v;
    }
    __syncthreads();

#pragma unroll 2
    for (int kp2 = 0; kp2 < 32; ++kp2) {
      h4 xv[8];
#pragma unroll
      for (int r = 0; r < 8; ++r)
        xv[r] = *(const h4*)(const void*)(xs + (size_t)(tr * 8 + r) * 64 + 2 * kp2);
      h8 w0a = *(const h8*)(const void*)(wsT + (size_t)(2 * kp2) * 256 + tg * 8);
      h8 w0b = *(const h8*)(const void*)(wsT + (size_t)(2 * kp2) * 256 + tg * 8 + 4);
      h8 w1a = *(const h8*)(const void*)(wsT + (size_t)(2 * kp2 + 1) * 256 + tg * 8);
      h8 w1b = *(const h8*)(const void*)(wsT + (size_t)(2 * kp2 + 1) * 256 + tg * 8 + 4);
#pragma unroll
      for (int r = 0; r < 8; ++r) {
        h2 x0 = sl2_4(xv[r], 0);
        h2 x1 = sl2_4(xv[r], 1);
#pragma unroll
        for (int g = 0; g < 4; ++g) {
          acc[r][g] = fdot2(x0, sl2(w0a, g), acc[r][g]);
          acc[r][g] = fdot2(x1, sl2(w1a, g), acc[r][g]);
        }
#pragma unroll
        for (int g = 0; g < 4; ++g) {
          acc[r][4 + g] = fdot2(x0, sl2(w0b, g), acc[r][4 + g]);
          acc[r][4 + g] = fdot2(x1, sl2(w1b, g), acc[r][4 + g]);
        }
      }
    }
    __syncthreads();
  }

  const float* bias = gb == 0 ? bf : gb == 1 ? bi : gb == 2 ? bg : bo;
  float bv[8];
#pragma unroll
  for (int g = 0; g < 8; ++g) bv[g] = bias[tg * 8 + g];
#pragma unroll
  for (int r = 0; r < 8; ++r) {
    h8 o;
#pragma unroll
    for (int g = 0; g < 8; ++g) o[g] = (_Float16)(acc[r][g] + bv[g]);
    *(h8*)(void*)(Xg + ((size_t)tb * NB + tr * 8 + r) * G4 + gb * DH + tg * 8) = o;
  }
}

// ---------------------------------------------------------------------------
// Phase 2: sequential LSTM. One workgroup per batch element (sync-free).
// 1024 threads, thread tid owns gate row gr == tid (gate = tid>>8, unit j = tid&255).
// Recurrent weights: K [0,192) f16 in registers, K [192,256) f16 in LDS.
// h (f16) broadcast from LDS each step.
// ---------------------------------------------------------------------------
__launch_bounds__(1024, 4)
__global__ void klstm(const _Float16* __restrict__ Xg,
                      const float* __restrict__ Wf, const float* __restrict__ Wi,
                      const float* __restrict__ Wg, const float* __restrict__ Wo,
                      const float* __restrict__ hsrc, const float* __restrict__ csrc,
                      float* __restrict__ out,
                      float* __restrict__ hN, float* __restrict__ cN,
                      int t0, int Tc) {
  __shared__ h8 wlds[NTAIL][1024];  // 8*1024*16B = 128KB, [chunk][tid] conflict-free
  __shared__ h2 hbuf[DH / 2];       // 512B current h (f16)
  __shared__ float acts[3][DH];     // i, g, o activations

  int tid = threadIdx.x;
  int b = blockIdx.x;
  int gate = tid >> 8;
  int j = tid & 255;

  const float* Wsel = gate == 0 ? Wf : gate == 1 ? Wi : gate == 2 ? Wg : Wo;
  const float* wr = Wsel + (size_t)j * DW + DIN;  // h-part of this row

  // load + convert recurrent weights: registers
  h2 wa[KRH];
#pragma unroll
  for (int q = 0; q < KR / 4; ++q) {
    f4 v = *(const f4*)(wr + 4 * q);
    h2 a; a[0] = (_Float16)v[0]; a[1] = (_Float16)v[1];
    h2 c2; c2[0] = (_Float16)v[2]; c2[1] = (_Float16)v[3];
    wa[2 * q] = a; wa[2 * q + 1] = c2;
  }
  // LDS tail
#pragma unroll
  for (int cc = 0; cc < NTAIL; ++cc) {
    f4 v = *(const f4*)(wr + KR + 8 * cc);
    f4 v2 = *(const f4*)(wr + KR + 8 * cc + 4);
    h8 w;
    w[0] = (_Float16)v[0]; w[1] = (_Float16)v[1]; w[2] = (_Float16)v[2]; w[3] = (_Float16)v[3];
    w[4] = (_Float16)v2[0]; w[5] = (_Float16)v2[1]; w[6] = (_Float16)v2[2]; w[7] = (_Float16)v2[3];
    wlds[cc][tid] = w;
  }

  float creg = 0.f;
  if (gate == 0) creg = csrc[(size_t)b * DH + j];
  if (tid < 128) {
    h2 hv;
    hv[0] = (_Float16)hsrc[(size_t)b * DH + 2 * tid];
    hv[1] = (_Float16)hsrc[(size_t)b * DH + 2 * tid + 1];
    hbuf[tid] = hv;
  }
  __syncthreads();

  const size_t xstep = (size_t)NB * G4;
  const _Float16* xp = Xg + (size_t)b * G4 + tid;
  float xcur = (float)xp[0];
  float hlast = 0.f;

  for (int t = 0; t < Tc; ++t) {
    float xnext = (t + 1 < Tc) ? (float)xp[(size_t)(t + 1) * xstep] : 0.f;
    float acc = xcur;  // x-part + bias (precomputed)
#pragma unroll
    for (int q = 0; q < KRH / 4; ++q) {
      h8 hv = *(const h8*)(const void*)(hbuf + 4 * q);  // broadcast 16B
      acc = fdot2(wa[4 * q + 0], sl2(hv, 0), acc);
      acc = fdot2(wa[4 * q + 1], sl2(hv, 1), acc);
      acc = fdot2(wa[4 * q + 2], sl2(hv, 2), acc);
      acc = fdot2(wa[4 * q + 3], sl2(hv, 3), acc);
    }
#pragma unroll
    for (int cc = 0; cc < NTAIL; ++cc) {
      h8 hv = *(const h8*)(const void*)(hbuf + KRH + 4 * cc);  // broadcast
      h8 wv = wlds[cc][tid];
      acc = fdot2(sl2(wv, 0), sl2(hv, 0), acc);
      acc = fdot2(sl2(wv, 1), sl2(hv, 1), acc);
      acc = fdot2(sl2(wv, 2), sl2(hv, 2), acc);
      acc = fdot2(sl2(wv, 3), sl2(hv, 3), acc);
    }

    if (gate == 1)      acts[0][j] = sigmoid_(acc);
    else if (gate == 2) acts[1][j] = tanh_(acc);
    else if (gate == 3) acts[2][j] = sigmoid_(acc);
    __syncthreads();
    if (gate == 0) {
      float f_ = sigmoid_(acc);
      float i_ = acts[0][j], g_ = acts[1][j], o_ = acts[2][j];
      creg = f_ * creg + i_ * g_;
      float hn = o_ * tanh_(creg);
      hlast = hn;
      out[((size_t)(t0 + t) * NB + b) * DH + j] = hn;
      ((_Float16*)hbuf)[j] = (_Float16)hn;
    }
    xcur = xnext;
    __syncthreads();
  }

  if (gate == 0) {
    hN[(size_t)b * DH + j] = hlast;
    cN[(size_t)b * DH + j] = creg;
  }
}

// ---------------------------------------------------------------------------
extern "C" void kernel_launch(void* const* d_in, const int* in_sizes, int n_in,
                              void* d_out, int out_size, void* d_ws, size_t ws_size,
                              hipStream_t stream) {
  if (n_in < 11) return;
  const float* x  = (const float*)d_in[0];
  const float* h0 = (const float*)d_in[1];
  const float* c0 = (const float*)d_in[2];
  const float* Wf = (const float*)d_in[3];
  const float* bf = (const float*)d_in[4];
  const float* Wi = (const float*)d_in[5];
  const float* bi = (const float*)d_in[6];
  const float* Wg = (const float*)d_in[7];
  const float* bg = (const float*)d_in[8];
  const float* Wo = (const float*)d_in[9];
  const float* bo = (const float*)d_in[10];

  float* out = (float*)d_out;
  float* hN = out + (size_t)T_STEPS * NB * DH;
  float* cN = hN + (size_t)NB * DH;

  // ws layout: [Xg ring: Tc*64*1024*2B][wxhT: 512KB]
  const size_t wxhBytes = (size_t)128 * G4 * sizeof(h2);  // 512KB
  size_t avail = (ws_size > wxhBytes + 256) ? ws_size - wxhBytes - 256 : 0;
  const size_t perT = (size_t)NB * G4 * 2;  // 128KB per time step
  int Tc = (int)(avail / perT);
  if (Tc > T_STEPS) Tc = T_STEPS;
  if (Tc < 1) Tc = 1;

  _Float16* Xg = (_Float16*)d_ws;
  size_t xgBytes = ((size_t)Tc * perT + 255) / 256 * 256;
  h2* wxhT = (h2*)((char*)d_ws + xgBytes);

  kconv_w<<<dim3(512), dim3(256), 0, stream>>>(Wf, Wi, Wg, Wo, wxhT);

  for (int t0 = 0; t0 < T_STEPS; t0 += Tc) {
    int tc = (T_STEPS - t0 < Tc) ? (T_STEPS - t0) : Tc;
    kxgemm<<<dim3(tc * 4), dim3(256), 0, stream>>>(x, wxhT, bf, bi, bg, bo, Xg, t0);
    const float* hs = (t0 == 0) ? h0 : hN;
    const float* cs = (t0 == 0) ? c0 : cN;
    klstm<<<dim3(NB), dim3(1024), 0, stream>>>(Xg, Wf, Wi, Wg, Wo, hs, cs,
                                               out, hN, cN, t0, tc);
  }
}